// Round 1
// baseline (108.966 us; speedup 1.0000x reference)
//
#include <hip/hip_runtime.h>

#define D_IN  128
#define D_MID 256
#define D_OUT 16
#define NB    512
#define NN    8192
#define NROWS (NB + NN)   // 8704

// ---------------- Kernel 1: Ew[row][16] = relu(row @ W1^T) @ W2^T ----------------
// 256 threads, 32 rows per block, 272 blocks.
__global__ __launch_bounds__(256) void mlp_kernel(
    const float* __restrict__ x, const float* __restrict__ calc_X,
    const float* __restrict__ W1, const float* __restrict__ W2,
    float* __restrict__ Ew)
{
    __shared__ float rows[32][132];     // padded: bank stride 4/row, 16B aligned
    __shared__ float hidden[32][264];   // padded: bank stride 8/row, 16B aligned

    const int t = threadIdx.x;
    const int row0 = blockIdx.x * 32;

    // ---- stage 32 input rows (coalesced float4) ----
#pragma unroll
    for (int i = 0; i < 4; ++i) {
        int idx = t + 256 * i;          // float4 index 0..1023
        int r   = idx >> 5;             // row 0..31
        int k4  = idx & 31;             // float4 within row
        int grow = row0 + r;
        const float* src = (grow < NB) ? (x + (size_t)grow * D_IN)
                                       : (calc_X + (size_t)(grow - NB) * D_IN);
        float4 v = reinterpret_cast<const float4*>(src)[k4];
        *reinterpret_cast<float4*>(&rows[r][k4 * 4]) = v;
    }
    __syncthreads();

    const int tx = t & 31;
    const int ty = t >> 5;      // 0..7
    const int r0 = ty * 4;

    // ---- phase 1: hidden = relu(rows @ W1^T), j-tiled so W1 stays L1-resident ----
    for (int q = 0; q < 8; ++q) {
        const int j = tx + 32 * q;
        const float4* w1row = reinterpret_cast<const float4*>(W1) + (size_t)j * 32;
        float acc0 = 0.f, acc1 = 0.f, acc2 = 0.f, acc3 = 0.f;
#pragma unroll 4
        for (int k4 = 0; k4 < 32; ++k4) {
            const float4 wv = w1row[k4];
            const float4 a0 = *reinterpret_cast<const float4*>(&rows[r0 + 0][k4 * 4]);
            const float4 a1 = *reinterpret_cast<const float4*>(&rows[r0 + 1][k4 * 4]);
            const float4 a2 = *reinterpret_cast<const float4*>(&rows[r0 + 2][k4 * 4]);
            const float4 a3 = *reinterpret_cast<const float4*>(&rows[r0 + 3][k4 * 4]);
            acc0 = fmaf(a0.x, wv.x, fmaf(a0.y, wv.y, fmaf(a0.z, wv.z, fmaf(a0.w, wv.w, acc0))));
            acc1 = fmaf(a1.x, wv.x, fmaf(a1.y, wv.y, fmaf(a1.z, wv.z, fmaf(a1.w, wv.w, acc1))));
            acc2 = fmaf(a2.x, wv.x, fmaf(a2.y, wv.y, fmaf(a2.z, wv.z, fmaf(a2.w, wv.w, acc2))));
            acc3 = fmaf(a3.x, wv.x, fmaf(a3.y, wv.y, fmaf(a3.z, wv.z, fmaf(a3.w, wv.w, acc3))));
        }
        hidden[r0 + 0][j] = fmaxf(acc0, 0.f);
        hidden[r0 + 1][j] = fmaxf(acc1, 0.f);
        hidden[r0 + 2][j] = fmaxf(acc2, 0.f);
        hidden[r0 + 3][j] = fmaxf(acc3, 0.f);
    }
    __syncthreads();

    // ---- phase 2: Ew = hidden @ W2^T  (d = o%16 -> 16-lane LDS broadcast, no conflicts) ----
#pragma unroll
    for (int o = t; o < 512; o += 256) {
        const int d = o & 15;
        const int r = o >> 4;
        const float4* w2row = reinterpret_cast<const float4*>(W2) + (size_t)d * 64;
        float acc = 0.f;
#pragma unroll 8
        for (int k4 = 0; k4 < 64; ++k4) {
            const float4 wv = w2row[k4];
            const float4 hv = *reinterpret_cast<const float4*>(&hidden[r][k4 * 4]);
            acc = fmaf(hv.x, wv.x, fmaf(hv.y, wv.y, fmaf(hv.z, wv.z, fmaf(hv.w, wv.w, acc))));
        }
        Ew[(size_t)(row0 + r) * D_OUT + d] = acc;
    }
}

// ---------------- Kernel 2: out[b][d] = sum_n Y[n][d]*w / sum_n w,
//                  w = exp(-0.5*((Xw[n][d]-Zw[b][d])/h)^2) ----------------
// 512 threads, 2 query rows (b) per block, 256 blocks.
#define GAUSS(xc, yc, zc, num, den) { \
    float df_ = (xc) - (zc); float ex_ = df_ * df_ * C; float w_; \
    asm("v_exp_f32 %0, %1" : "=v"(w_) : "v"(ex_)); \
    (den) += w_; (num) = fmaf(w_, (yc), (num)); }

__global__ __launch_bounds__(512) void kde_kernel(
    const float* __restrict__ Ew, const float* __restrict__ Y,
    const float* __restrict__ hptr, float* __restrict__ out)
{
    __shared__ float red[8][4][16];

    const int t  = threadIdx.x;
    const int b0 = blockIdx.x * 2;
    const float* __restrict__ Xw = Ew + (size_t)NB * D_OUT;

    const float hv = hptr[0];
    const float C = -0.72134752044448170368f / (hv * hv);  // -log2(e)/2 / h^2

    const int dg    = t & 3;     // float4 group within the 16 dims
    const int chunk = t >> 2;    // 0..127

    const float4 z0 = reinterpret_cast<const float4*>(Ew + (size_t)b0 * D_OUT)[dg];
    const float4 z1 = reinterpret_cast<const float4*>(Ew + (size_t)(b0 + 1) * D_OUT)[dg];

    float4 num0 = {0,0,0,0}, num1 = {0,0,0,0};
    float4 den0 = {0,0,0,0}, den1 = {0,0,0,0};

#pragma unroll 2
    for (int i = 0; i < 64; ++i) {
        const int n = chunk + 128 * i;   // wave covers 16 consecutive rows -> 1KB/instr
        const float4 xw = reinterpret_cast<const float4*>(Xw + (size_t)n * D_OUT)[dg];
        const float4 y  = reinterpret_cast<const float4*>(Y  + (size_t)n * D_OUT)[dg];
        GAUSS(xw.x, y.x, z0.x, num0.x, den0.x);
        GAUSS(xw.y, y.y, z0.y, num0.y, den0.y);
        GAUSS(xw.z, y.z, z0.z, num0.z, den0.z);
        GAUSS(xw.w, y.w, z0.w, num0.w, den0.w);
        GAUSS(xw.x, y.x, z1.x, num1.x, den1.x);
        GAUSS(xw.y, y.y, z1.y, num1.y, den1.y);
        GAUSS(xw.z, y.z, z1.z, num1.z, den1.z);
        GAUSS(xw.w, y.w, z1.w, num1.w, den1.w);
    }

    // ---- reduce over chunks: butterfly within wave (lanes sharing dg) ----
    float vals[16] = { num0.x, num0.y, num0.z, num0.w,
                       num1.x, num1.y, num1.z, num1.w,
                       den0.x, den0.y, den0.z, den0.w,
                       den1.x, den1.y, den1.z, den1.w };
#pragma unroll
    for (int m = 4; m <= 32; m <<= 1) {
#pragma unroll
        for (int v = 0; v < 16; ++v)
            vals[v] += __shfl_xor(vals[v], m, 64);
    }

    const int wave = t >> 6;
    const int lane = t & 63;
    if (lane < 4) {
#pragma unroll
        for (int v = 0; v < 16; ++v) red[wave][lane][v] = vals[v];
    }
    __syncthreads();

    if (t < 32) {
        const int b = t >> 4;        // 0/1
        const int d = t & 15;
        const int dgrp = d >> 2;
        const int j = d & 3;
        float num = 0.f, den = 0.f;
#pragma unroll
        for (int w = 0; w < 8; ++w) {
            num += red[w][dgrp][b * 4 + j];
            den += red[w][dgrp][8 + b * 4 + j];
        }
        out[(size_t)(b0 + b) * D_OUT + d] = num / den;
    }
}

extern "C" void kernel_launch(void* const* d_in, const int* in_sizes, int n_in,
                              void* d_out, int out_size, void* d_ws, size_t ws_size,
                              hipStream_t stream) {
    const float* x      = (const float*)d_in[0];
    const float* calc_X = (const float*)d_in[1];
    const float* calc_Y = (const float*)d_in[2];
    const float* W1     = (const float*)d_in[3];
    const float* W2     = (const float*)d_in[4];
    const float* h      = (const float*)d_in[5];
    float* Ew  = (float*)d_ws;           // [8704][16] f32 = 557 KB
    float* out = (float*)d_out;          // [512][16] f32

    mlp_kernel<<<dim3(NROWS / 32), dim3(256), 0, stream>>>(x, calc_X, W1, W2, Ew);
    kde_kernel<<<dim3(NB / 2), dim3(512), 0, stream>>>(Ew, calc_Y, h, out);
}

// Round 2
// 62.254 us; speedup vs baseline: 1.7503x; 1.7503x over previous
//
#include <hip/hip_runtime.h>

#define D_IN  128
#define D_MID 256
#define D_OUT 16
#define NB    512
#define NN    8192
#define NROWS (NB + NN)   // 8704
#define RPB   8           // rows per MLP block
#define BT    4           // query rows per KDE block
#define NSLICE 4          // n-slices for KDE
#define SLICE_N (NN / NSLICE)

// ws layout (floats): Ew[8704*16] | partial[2*NSLICE*NB*16] | W1T4[32768]
#define EW_OFF      0
#define PART_OFF    (NROWS * D_OUT)                 // 139264
#define PART_DEN    (PART_OFF + NSLICE * NB * D_OUT) // +32768
#define W1T_OFF     (PART_OFF + 2 * NSLICE * NB * D_OUT)

// ---------------- Kernel 0: W1T4[k4][j] = float4{W1[j][4k4..4k4+3]} ----------------
__global__ __launch_bounds__(256) void transpose_kernel(
    const float* __restrict__ W1, float* __restrict__ W1T)
{
    const int tid = blockIdx.x * 256 + threadIdx.x;   // 0..8191 (float4 units)
    const int k4 = tid >> 8;                          // 0..31
    const int j  = tid & 255;                         // 0..255
    const float4 v = reinterpret_cast<const float4*>(W1)[(size_t)j * 32 + k4];
    reinterpret_cast<float4*>(W1T)[(size_t)k4 * 256 + j] = v;
}

// ---------------- Kernel 1: Ew[row][16] = relu(row @ W1^T) @ W2^T ----------------
// 256 threads, 8 rows per block, 1088 blocks.
__global__ __launch_bounds__(256, 4) void mlp_kernel(
    const float* __restrict__ x, const float* __restrict__ calc_X,
    const float* __restrict__ W1T, const float* __restrict__ W2,
    float* __restrict__ Ew)
{
    __shared__ float rows[RPB][132];     // 132*4 = 528 B stride (16B aligned)
    __shared__ float hidden[RPB][264];

    const int t = threadIdx.x;
    const int row0 = blockIdx.x * RPB;

    // ---- stage 8 rows: 256 float4s, one per thread (coalesced) ----
    {
        const int r  = t >> 5;
        const int k4 = t & 31;
        const int grow = row0 + r;
        const float* src = (grow < NB) ? (x + (size_t)grow * D_IN)
                                       : (calc_X + (size_t)(grow - NB) * D_IN);
        const float4 v = reinterpret_cast<const float4*>(src)[k4];
        *reinterpret_cast<float4*>(&rows[r][k4 * 4]) = v;
    }
    __syncthreads();

    // ---- phase 1: hidden[r][j] = relu(rows[r] . W1[j]), j = t ----
    {
        const float4* __restrict__ w1t4 = reinterpret_cast<const float4*>(W1T);
        float acc[RPB] = {0.f, 0.f, 0.f, 0.f, 0.f, 0.f, 0.f, 0.f};
#pragma unroll 4
        for (int k4 = 0; k4 < 32; ++k4) {
            const float4 wv = w1t4[k4 * 256 + t];     // fully coalesced, 1KB/wave-instr
#pragma unroll
            for (int r = 0; r < RPB; ++r) {
                const float4 a = *reinterpret_cast<const float4*>(&rows[r][k4 * 4]); // broadcast
                acc[r] = fmaf(a.x, wv.x, fmaf(a.y, wv.y, fmaf(a.z, wv.z, fmaf(a.w, wv.w, acc[r]))));
            }
        }
#pragma unroll
        for (int r = 0; r < RPB; ++r) hidden[r][t] = fmaxf(acc[r], 0.f);
    }
    __syncthreads();

    // ---- phase 2: Ew = hidden @ W2^T; thread pair splits k, shfl-combine ----
    {
        const int o    = t >> 1;          // 0..127 output index
        const int half = t & 1;
        const int r = o >> 4;
        const int d = o & 15;
        const float4* w2row = reinterpret_cast<const float4*>(W2) + (size_t)d * 64 + half * 32;
        const float* hrow = &hidden[r][half * 128];
        float acc = 0.f;
#pragma unroll 8
        for (int k4 = 0; k4 < 32; ++k4) {
            const float4 wv = w2row[k4];
            const float4 hv = *reinterpret_cast<const float4*>(&hrow[k4 * 4]);
            acc = fmaf(hv.x, wv.x, fmaf(hv.y, wv.y, fmaf(hv.z, wv.z, fmaf(hv.w, wv.w, acc))));
        }
        acc += __shfl_xor(acc, 1, 64);
        if (half == 0) Ew[(size_t)(row0 + r) * D_OUT + d] = acc;
    }
}

// ---------------- Kernel 2: partial KDE sums over one n-slice ----------------
// grid (NB/BT, NSLICE), 512 threads.
#define GAUSS(xc, yc, zc, num, den) { \
    float df_ = (xc) - (zc); float ex_ = df_ * df_ * C; float w_; \
    asm("v_exp_f32 %0, %1" : "=v"(w_) : "v"(ex_)); \
    (den) += w_; (num) = fmaf(w_, (yc), (num)); }

__global__ __launch_bounds__(512, 4) void kde_kernel(
    const float* __restrict__ Ew, const float* __restrict__ Y,
    const float* __restrict__ hptr, float* __restrict__ partial)
{
    __shared__ float red[8][4][32];

    const int t     = threadIdx.x;
    const int b0    = blockIdx.x * BT;
    const int slice = blockIdx.y;
    const float* __restrict__ Xw = Ew + (size_t)NB * D_OUT;

    const float hv = hptr[0];
    const float C = -0.72134752044448170368f / (hv * hv);  // -log2(e)/2 / h^2

    const int dg    = t & 3;     // float4 group within the 16 dims
    const int chunk = t >> 2;    // 0..127

    float4 z[BT], num[BT], den[BT];
#pragma unroll
    for (int bt = 0; bt < BT; ++bt) {
        z[bt] = reinterpret_cast<const float4*>(Ew + (size_t)(b0 + bt) * D_OUT)[dg];
        num[bt] = make_float4(0.f, 0.f, 0.f, 0.f);
        den[bt] = make_float4(0.f, 0.f, 0.f, 0.f);
    }

#pragma unroll 2
    for (int i = 0; i < SLICE_N / 128; ++i) {   // 16 iterations
        const int n = slice * SLICE_N + chunk + 128 * i;
        const float4 xw = reinterpret_cast<const float4*>(Xw + (size_t)n * D_OUT)[dg];
        const float4 y  = reinterpret_cast<const float4*>(Y  + (size_t)n * D_OUT)[dg];
#pragma unroll
        for (int bt = 0; bt < BT; ++bt) {
            GAUSS(xw.x, y.x, z[bt].x, num[bt].x, den[bt].x);
            GAUSS(xw.y, y.y, z[bt].y, num[bt].y, den[bt].y);
            GAUSS(xw.z, y.z, z[bt].z, num[bt].z, den[bt].z);
            GAUSS(xw.w, y.w, z[bt].w, num[bt].w, den[bt].w);
        }
    }

    // ---- butterfly over chunk bits within wave (lanes sharing dg) ----
    float vals[32];
#pragma unroll
    for (int bt = 0; bt < BT; ++bt) {
        vals[bt * 4 + 0] = num[bt].x; vals[bt * 4 + 1] = num[bt].y;
        vals[bt * 4 + 2] = num[bt].z; vals[bt * 4 + 3] = num[bt].w;
        vals[16 + bt * 4 + 0] = den[bt].x; vals[16 + bt * 4 + 1] = den[bt].y;
        vals[16 + bt * 4 + 2] = den[bt].z; vals[16 + bt * 4 + 3] = den[bt].w;
    }
#pragma unroll
    for (int m = 4; m <= 32; m <<= 1) {
#pragma unroll
        for (int v = 0; v < 32; ++v)
            vals[v] += __shfl_xor(vals[v], m, 64);
    }

    const int wave = t >> 6;
    const int lane = t & 63;
    if (lane < 4) {
#pragma unroll
        for (int v = 0; v < 32; ++v) red[wave][lane][v] = vals[v];
    }
    __syncthreads();

    if (t < 64) {
        const int b = t >> 4;        // 0..3
        const int d = t & 15;
        const int dgrp = d >> 2;
        const int j = d & 3;
        float nsum = 0.f, dsum = 0.f;
#pragma unroll
        for (int w = 0; w < 8; ++w) {
            nsum += red[w][dgrp][b * 4 + j];
            dsum += red[w][dgrp][16 + b * 4 + j];
        }
        const size_t idx = (size_t)slice * NB * D_OUT + (size_t)(b0 + b) * D_OUT + d;
        partial[idx] = nsum;
        partial[(size_t)NSLICE * NB * D_OUT + idx] = dsum;
    }
}

// ---------------- Kernel 3: combine slices + divide ----------------
__global__ __launch_bounds__(256) void combine_kernel(
    const float* __restrict__ partial, float* __restrict__ out)
{
    const int i = blockIdx.x * 256 + threadIdx.x;   // 0..8191
    float nsum = 0.f, dsum = 0.f;
#pragma unroll
    for (int s = 0; s < NSLICE; ++s) {
        nsum += partial[(size_t)s * NB * D_OUT + i];
        dsum += partial[(size_t)(NSLICE + s) * NB * D_OUT + i];
    }
    out[i] = nsum / dsum;
}

extern "C" void kernel_launch(void* const* d_in, const int* in_sizes, int n_in,
                              void* d_out, int out_size, void* d_ws, size_t ws_size,
                              hipStream_t stream) {
    const float* x      = (const float*)d_in[0];
    const float* calc_X = (const float*)d_in[1];
    const float* calc_Y = (const float*)d_in[2];
    const float* W1     = (const float*)d_in[3];
    const float* W2     = (const float*)d_in[4];
    const float* h      = (const float*)d_in[5];

    float* ws      = (float*)d_ws;
    float* Ew      = ws + EW_OFF;
    float* partial = ws + PART_OFF;
    float* W1T     = ws + W1T_OFF;
    float* out     = (float*)d_out;

    transpose_kernel<<<dim3(32), dim3(256), 0, stream>>>(W1, W1T);
    mlp_kernel<<<dim3(NROWS / RPB), dim3(256), 0, stream>>>(x, calc_X, W1T, W2, Ew);
    kde_kernel<<<dim3(NB / BT, NSLICE), dim3(512), 0, stream>>>(Ew, calc_Y, h, partial);
    combine_kernel<<<dim3(NB * D_OUT / 256), dim3(256), 0, stream>>>(partial, out);
}

// Round 3
// 47.993 us; speedup vs baseline: 2.2705x; 1.2972x over previous
//
#include <hip/hip_runtime.h>

#define D_IN  128
#define D_MID 256
#define D_OUT 16
#define NB    512
#define NN    8192
#define NROWS (NB + NN)   // 8704
#define RPB   16          // rows per MLP block
#define BT    8           // query rows per KDE block
#define NSLICE 8          // n-slices for KDE
#define SLICE_N (NN / NSLICE)   // 1024

// ws layout (floats): Ews[8704*16] | partial[2*NSLICE*NB*16] | W1T4[32768] | W2T4[4096]
#define EW_OFF      0
#define PART_OFF    (NROWS * D_OUT)                       // 139264
#define W1T_OFF     (PART_OFF + 2 * NSLICE * NB * D_OUT)  // +131072
#define W2T_OFF     (W1T_OFF + D_MID * D_IN)              // +32768

// ---------------- Kernel 0: transpose W1 and W2 to coalesced layouts ----------------
// W1T4[k4*256 + j] = float4{W1[j][4k4..]},  W2T4[j4*16 + d] = float4{W2[d][4j4..]}
__global__ __launch_bounds__(256) void transpose_kernel(
    const float* __restrict__ W1, const float* __restrict__ W2,
    float* __restrict__ W1T, float* __restrict__ W2T)
{
    const int tid = blockIdx.x * 256 + threadIdx.x;
    if (tid < 8192) {
        const int k4 = tid >> 8;            // 0..31
        const int j  = tid & 255;           // 0..255
        const float4 v = reinterpret_cast<const float4*>(W1)[(size_t)j * 32 + k4];
        reinterpret_cast<float4*>(W1T)[(size_t)k4 * 256 + j] = v;
    } else {
        const int t2 = tid - 8192;          // 0..1023
        const int j4 = t2 >> 4;             // 0..63
        const int d  = t2 & 15;             // 0..15
        const float4 v = reinterpret_cast<const float4*>(W2)[(size_t)d * 64 + j4];
        reinterpret_cast<float4*>(W2T)[(size_t)j4 * 16 + d] = v;
    }
}

// ---------------- Kernel 1: Ews[row] = s * (relu(row @ W1^T) @ W2^T),  s = sqrt(log2e/2)/h ----
// 256 threads, 16 rows/block, 544 blocks. Each thread: 4 rows x 4 hidden-cols register tile.
__global__ __launch_bounds__(256) void mlp_kernel(
    const float* __restrict__ x, const float* __restrict__ calc_X,
    const float* __restrict__ W1T, const float* __restrict__ W2T,
    const float* __restrict__ hptr, float* __restrict__ Ews)
{
    __shared__ float rows[RPB][132];
    __shared__ float hid[RPB][260];

    const int t = threadIdx.x;
    const int row0 = blockIdx.x * RPB;

    // ---- stage 16 rows (512 float4s, 2 per thread, coalesced) ----
#pragma unroll
    for (int i = 0; i < 2; ++i) {
        const int idx = t + 256 * i;
        const int r  = idx >> 5;
        const int k4 = idx & 31;
        const int grow = row0 + r;
        const float* src = (grow < NB) ? (x + (size_t)grow * D_IN)
                                       : (calc_X + (size_t)(grow - NB) * D_IN);
        const float4 v = reinterpret_cast<const float4*>(src)[k4];
        *reinterpret_cast<float4*>(&rows[r][k4 * 4]) = v;
    }
    __syncthreads();

    const int jj = t & 63;      // lane-consecutive j
    const int rg = t >> 6;      // wave id -> row group (wave-uniform)

    // ---- phase 1: acc[q][s] = rows[rg*4+q] . W1[s*64+jj]  (64 fma per k4-step) ----
    {
        float acc[4][4] = {};
        const float4* __restrict__ w1t4 = reinterpret_cast<const float4*>(W1T);
#pragma unroll 2
        for (int k4 = 0; k4 < 32; ++k4) {
            float4 wv[4], av[4];
#pragma unroll
            for (int s = 0; s < 4; ++s)
                wv[s] = w1t4[k4 * 256 + s * 64 + jj];           // 1KB/wave, coalesced
#pragma unroll
            for (int q = 0; q < 4; ++q)
                av[q] = *reinterpret_cast<const float4*>(&rows[rg * 4 + q][k4 * 4]); // broadcast
#pragma unroll
            for (int q = 0; q < 4; ++q)
#pragma unroll
                for (int s = 0; s < 4; ++s)
                    acc[q][s] = fmaf(av[q].x, wv[s].x, fmaf(av[q].y, wv[s].y,
                                fmaf(av[q].z, wv[s].z, fmaf(av[q].w, wv[s].w, acc[q][s]))));
        }
#pragma unroll
        for (int q = 0; q < 4; ++q)
#pragma unroll
            for (int s = 0; s < 4; ++s)
                hid[rg * 4 + q][s * 64 + jj] = fmaxf(acc[q][s], 0.f);
    }
    __syncthreads();

    // ---- phase 2: Ews[r][d] = s * (hid[r] . W2[d]) ----
    {
        const int r = t >> 4;       // 0..15
        const int d = t & 15;
        const float4* __restrict__ w2t4 = reinterpret_cast<const float4*>(W2T);
        float acc = 0.f;
#pragma unroll 4
        for (int j4 = 0; j4 < 64; ++j4) {
            const float4 wv = w2t4[j4 * 16 + d];                 // 256B contig + bcast
            const float4 hv = *reinterpret_cast<const float4*>(&hid[r][j4 * 4]);
            acc = fmaf(hv.x, wv.x, fmaf(hv.y, wv.y, fmaf(hv.z, wv.z, fmaf(hv.w, wv.w, acc))));
        }
        const float scale = 0.84932180028801904272f / hptr[0];   // sqrt(log2(e)/2)/h
        Ews[(size_t)(row0 + r) * D_OUT + d] = acc * scale;
    }
}

// ---------------- Kernel 2: partial KDE sums over one n-slice ----------------
// grid (NB/BT, NSLICE), 256 threads. w = exp2(-(xs - zs)^2), everything pre-scaled.
#define GAUSS(xc, yc, zc, num, den) { \
    const float df_ = (xc) - (zc); \
    const float w_ = __builtin_amdgcn_exp2f(-(df_ * df_)); \
    (den) += w_; (num) = fmaf(w_, (yc), (num)); }

__global__ __launch_bounds__(256) void kde_kernel(
    const float* __restrict__ Ews, const float* __restrict__ Y,
    float* __restrict__ partial)
{
    __shared__ float red[4][4][64];

    const int t     = threadIdx.x;
    const int b0    = blockIdx.x * BT;
    const int slice = blockIdx.y;
    const float* __restrict__ Xws = Ews + (size_t)NB * D_OUT;

    const int dg    = t & 3;     // float4 group within the 16 dims
    const int chunk = t >> 2;    // 0..63

    float4 z[BT], num[BT], den[BT];
#pragma unroll
    for (int bt = 0; bt < BT; ++bt) {
        z[bt] = reinterpret_cast<const float4*>(Ews + (size_t)(b0 + bt) * D_OUT)[dg];
        num[bt] = make_float4(0.f, 0.f, 0.f, 0.f);
        den[bt] = make_float4(0.f, 0.f, 0.f, 0.f);
    }

#pragma unroll 2
    for (int i = 0; i < SLICE_N / 64; ++i) {      // 16 iterations
        const int n = slice * SLICE_N + chunk + 64 * i;
        const float4 xw = reinterpret_cast<const float4*>(Xws + (size_t)n * D_OUT)[dg];
        const float4 y  = reinterpret_cast<const float4*>(Y   + (size_t)n * D_OUT)[dg];
#pragma unroll
        for (int bt = 0; bt < BT; ++bt) {
            GAUSS(xw.x, y.x, z[bt].x, num[bt].x, den[bt].x);
            GAUSS(xw.y, y.y, z[bt].y, num[bt].y, den[bt].y);
            GAUSS(xw.z, y.z, z[bt].z, num[bt].z, den[bt].z);
            GAUSS(xw.w, y.w, z[bt].w, num[bt].w, den[bt].w);
        }
    }

    // ---- butterfly over chunk bits 0..3 within wave (lanes sharing dg) ----
    float vals[64];
#pragma unroll
    for (int bt = 0; bt < BT; ++bt) {
        vals[bt * 4 + 0] = num[bt].x; vals[bt * 4 + 1] = num[bt].y;
        vals[bt * 4 + 2] = num[bt].z; vals[bt * 4 + 3] = num[bt].w;
        vals[32 + bt * 4 + 0] = den[bt].x; vals[32 + bt * 4 + 1] = den[bt].y;
        vals[32 + bt * 4 + 2] = den[bt].z; vals[32 + bt * 4 + 3] = den[bt].w;
    }
#pragma unroll
    for (int m = 4; m <= 32; m <<= 1) {
#pragma unroll
        for (int v = 0; v < 64; ++v)
            vals[v] += __shfl_xor(vals[v], m, 64);
    }

    const int wave = t >> 6;
    const int lane = t & 63;
    if (lane < 4) {
#pragma unroll
        for (int v = 0; v < 64; ++v) red[wave][lane][v] = vals[v];
    }
    __syncthreads();

    if (t < 128) {
        const int b = t >> 4;        // 0..7
        const int d = t & 15;
        float nsum = 0.f, dsum = 0.f;
#pragma unroll
        for (int w = 0; w < 4; ++w) {
            nsum += red[w][d >> 2][b * 4 + (d & 3)];
            dsum += red[w][d >> 2][32 + b * 4 + (d & 3)];
        }
        const size_t idx = (size_t)slice * NB * D_OUT + (size_t)(b0 + b) * D_OUT + d;
        partial[idx] = nsum;
        partial[(size_t)NSLICE * NB * D_OUT + idx] = dsum;
    }
}

// ---------------- Kernel 3: combine slices + divide ----------------
__global__ __launch_bounds__(256) void combine_kernel(
    const float* __restrict__ partial, float* __restrict__ out)
{
    const int i = blockIdx.x * 256 + threadIdx.x;   // 0..8191
    float nsum = 0.f, dsum = 0.f;
#pragma unroll
    for (int s = 0; s < NSLICE; ++s) {
        nsum += partial[(size_t)s * NB * D_OUT + i];
        dsum += partial[(size_t)(NSLICE + s) * NB * D_OUT + i];
    }
    out[i] = nsum / dsum;
}

extern "C" void kernel_launch(void* const* d_in, const int* in_sizes, int n_in,
                              void* d_out, int out_size, void* d_ws, size_t ws_size,
                              hipStream_t stream) {
    const float* x      = (const float*)d_in[0];
    const float* calc_X = (const float*)d_in[1];
    const float* calc_Y = (const float*)d_in[2];
    const float* W1     = (const float*)d_in[3];
    const float* W2     = (const float*)d_in[4];
    const float* h      = (const float*)d_in[5];

    float* ws      = (float*)d_ws;
    float* Ews     = ws + EW_OFF;
    float* partial = ws + PART_OFF;
    float* W1T     = ws + W1T_OFF;
    float* W2T     = ws + W2T_OFF;
    float* out     = (float*)d_out;

    transpose_kernel<<<dim3(36), dim3(256), 0, stream>>>(W1, W2, W1T, W2T);
    mlp_kernel<<<dim3(NROWS / RPB), dim3(256), 0, stream>>>(x, calc_X, W1T, W2T, h, Ews);
    kde_kernel<<<dim3(NB / BT, NSLICE), dim3(256), 0, stream>>>(Ews, calc_Y, partial);
    combine_kernel<<<dim3(NB * D_OUT / 256), dim3(256), 0, stream>>>(partial, out);
}